// Round 7
// baseline (125.485 us; speedup 1.0000x reference)
//
#include <hip/hip_runtime.h>
#include <stdint.h>

#define BATCH 256
#define IDIM  8192
#define ODIM  8192
#define MS    64
#define IC    128
#define OC    128
#define NB    1024

#define TM 256
#define TN 256
#define KSPLIT 8
#define NIB (IC / KSPLIT)      // 16 ib-iterations per workgroup

typedef __bf16 bf16x8 __attribute__((ext_vector_type(8)));
typedef float  floatx4 __attribute__((ext_vector_type(4)));

// s_waitcnt imm: vmcnt[3:0]|[15:14], expcnt [6:4]=dont-care, lgkmcnt [11:8]=dont-care
#define WAITCNT_VM(n) ((((n) & 15) | (((n) >> 4) << 14)) | 0x70 | 0xF00)

__device__ __forceinline__ void async_load16(unsigned short* lds_p, const unsigned short* g_p) {
    __builtin_amdgcn_global_load_lds(
        (const __attribute__((address_space(1))) unsigned int*)g_p,
        (__attribute__((address_space(3))) unsigned int*)lds_p,
        16, 0, 0);
}

__device__ __forceinline__ unsigned short f32_to_bf16(float f) {
    unsigned int u = __float_as_uint(f);
    u += 0x7FFFu + ((u >> 16) & 1u);
    return (unsigned short)(u >> 16);
}

// ---- kernel 1: blocks -> bf16 [b][c][r] | x -> bf16 row-major | parts -> pT[ob][ib] ----
#define XCONV_BLKS 1024
#define PT_BLKS 64
__global__ void k_convert(const float* __restrict__ x, const float* __restrict__ blocks,
                          const int* __restrict__ parts,
                          unsigned short* __restrict__ xb, unsigned short* __restrict__ bt,
                          int* __restrict__ pT) {
    __shared__ float tile[MS][MS + 1];
    int b = blockIdx.x;
    if (b < NB) {
        const float4* src4 = (const float4*)(blocks + (size_t)b * MS * MS);
        unsigned short* dst = bt + (size_t)b * MS * MS;
        #pragma unroll
        for (int i = 0; i < 4; ++i) {
            int slot = i * 256 + threadIdx.x;
            int r = slot >> 4, c4 = (slot & 15) * 4;
            float4 v = src4[slot];
            tile[r][c4 + 0] = v.x; tile[r][c4 + 1] = v.y;
            tile[r][c4 + 2] = v.z; tile[r][c4 + 3] = v.w;
        }
        __syncthreads();
        #pragma unroll
        for (int i = 0; i < 2; ++i) {
            int slot = i * 256 + threadIdx.x;
            int c = slot >> 3, o = slot & 7;
            union { unsigned short s[8]; uint4 v; } u;
            #pragma unroll
            for (int j = 0; j < 8; ++j) u.s[j] = f32_to_bf16(tile[o * 8 + j][c]);
            *(uint4*)(dst + c * MS + o * 8) = u.v;
        }
    } else if (b < NB + XCONV_BLKS) {
        int t = (b - NB) * 256 + threadIdx.x;
        const float4* x4 = (const float4*)x;
        float4 a = x4[2 * t], bb = x4[2 * t + 1];
        union { unsigned short s[8]; uint4 v; } u;
        u.s[0] = f32_to_bf16(a.x);  u.s[1] = f32_to_bf16(a.y);
        u.s[2] = f32_to_bf16(a.z);  u.s[3] = f32_to_bf16(a.w);
        u.s[4] = f32_to_bf16(bb.x); u.s[5] = f32_to_bf16(bb.y);
        u.s[6] = f32_to_bf16(bb.z); u.s[7] = f32_to_bf16(bb.w);
        ((uint4*)xb)[t] = u.v;
    } else {
        int t = (b - NB - XCONV_BLKS) * 256 + threadIdx.x;   // 16384
        int oc = t >> 7, ic = t & 127;
        pT[t] = parts[ic * OC + oc];                          // pT[ob][ib]
    }
}

// ---- kernel 2: GEMM 256x256 tile, 16 waves of 64x64, dbuf LDS, raw barrier + vmcnt(4) ----
// Traffic-minimal: B-gather read exactly once (TM=BATCH), A read 32x (TN=256).
// LDS XOR swizzle (verified 0 conflicts): LDS[r][oct] = global[r][oct ^ (r&7)]
__global__ __launch_bounds__(1024, 1)
void k_mosaic_gemm(const unsigned short* __restrict__ xb,
                   const unsigned short* __restrict__ bt,
                   const int* __restrict__ pT,
                   float* __restrict__ partial) {
    __shared__ __align__(16) unsigned short a_lds[2][TM * MS];   // 2 x 32 KB
    __shared__ __align__(16) unsigned short b_lds[2][TN * MS];   // 2 x 32 KB

    const int tid  = threadIdx.x;
    const int lane = tid & 63;
    const int wave = tid >> 6;       // 0..15
    const int wrow = wave >> 2;      // 0..3 : 64-row band
    const int wcol = wave & 3;       // 0..3 : 64-col band
    const int nt = blockIdx.x;       // 0..31
    const int ks = blockIdx.y;       // 0..7

    const int ob0 = nt * 4;
    const int ib0 = ks * NIB;

    const int row  = lane & 15;
    const int quad = lane >> 4;

    // preload this wg's 64 part indices: lane L holds pT[(ob0 + L>>4)][ib0 + (L&15)]
    int pv = pT[(ob0 + (lane >> 4)) * IC + ib0 + (lane & 15)];

    // iteration-invariant ds_read element offsets
    int a_off[2][4], b_off[2][4];
    #pragma unroll
    for (int kk = 0; kk < 2; ++kk) {
        int oct = kk * 4 + quad;
        #pragma unroll
        for (int mi = 0; mi < 4; ++mi) {
            int r = wrow * 64 + mi * 16 + row;
            a_off[kk][mi] = r * MS + ((oct ^ (r & 7)) << 3);
        }
        #pragma unroll
        for (int ni = 0; ni < 4; ++ni) {
            int n = wcol * 64 + ni * 16 + row;
            b_off[kk][ni] = n * MS + ((oct ^ (n & 7)) << 3);
        }
    }

    floatx4 acc[4][4];
    #pragma unroll
    for (int mi = 0; mi < 4; ++mi)
        #pragma unroll
        for (int ni = 0; ni < 4; ++ni)
            acc[mi][ni] = (floatx4){0.f, 0.f, 0.f, 0.f};

    // 4 global_load_lds per thread per STAGE (2 A + 2 B) — vmcnt counting relies on this
#define STAGE(buf, ib_, q0, q1, q2, q3) do {                                  \
    _Pragma("unroll")                                                         \
    for (int j = 0; j < 2; ++j) {                                             \
        int slot = j * 1024 + tid;                                            \
        int m = slot >> 3;                                                    \
        int oct = (slot & 7) ^ (m & 7);                                       \
        async_load16(&a_lds[buf][slot * 8],                                   \
                     xb + (size_t)m * IDIM + (ib_) * MS + oct * 8);           \
    }                                                                         \
    _Pragma("unroll")                                                         \
    for (int j = 0; j < 2; ++j) {                                             \
        int slot = j * 1024 + tid;                                            \
        int n = slot >> 3;                                                    \
        int oct = (slot & 7) ^ (n & 7);                                       \
        int p = (j == 0) ? ((tid < 512) ? (q0) : (q1))                        \
                         : ((tid < 512) ? (q2) : (q3));                       \
        async_load16(&b_lds[buf][slot * 8],                                   \
                     bt + (size_t)p * (MS * MS) + (n & 63) * MS + oct * 8);   \
    } } while (0)

#define COMPUTE(buf) do {                                                     \
    _Pragma("unroll")                                                         \
    for (int kk = 0; kk < 2; ++kk) {                                          \
        bf16x8 af[4], bfr[4];                                                 \
        _Pragma("unroll")                                                     \
        for (int mi = 0; mi < 4; ++mi)                                        \
            af[mi] = *(const bf16x8*)&a_lds[buf][a_off[kk][mi]];              \
        _Pragma("unroll")                                                     \
        for (int ni = 0; ni < 4; ++ni)                                        \
            bfr[ni] = *(const bf16x8*)&b_lds[buf][b_off[kk][ni]];             \
        _Pragma("unroll")                                                     \
        for (int mi = 0; mi < 4; ++mi)                                        \
            _Pragma("unroll")                                                 \
            for (int ni = 0; ni < 4; ++ni)                                    \
                acc[mi][ni] = __builtin_amdgcn_mfma_f32_16x16x32_bf16(        \
                    af[mi], bfr[ni], acc[mi][ni], 0, 0, 0);                   \
    } } while (0)

    // prologue: stage iter 0 into buf 0
    {
        int q0 = __shfl(pv, 0), q1 = __shfl(pv, 16), q2 = __shfl(pv, 32), q3 = __shfl(pv, 48);
        STAGE(0, ib0 + 0, q0, q1, q2, q3);
    }

    for (int i = 0; i < NIB - 1; ++i) {
        int q0 = __shfl(pv, i + 1),      q1 = __shfl(pv, 16 + i + 1);
        int q2 = __shfl(pv, 32 + i + 1), q3 = __shfl(pv, 48 + i + 1);
        STAGE((i + 1) & 1, ib0 + i + 1, q0, q1, q2, q3);  // prefetch next
        __builtin_amdgcn_s_waitcnt(WAITCNT_VM(4));        // drain iter i's loads only
        __builtin_amdgcn_s_barrier();
        COMPUTE(i & 1);
        __builtin_amdgcn_s_barrier();                      // all waves done before overwrite
    }
    __builtin_amdgcn_s_waitcnt(WAITCNT_VM(0));
    __builtin_amdgcn_s_barrier();
    COMPUTE((NIB - 1) & 1);

    // epilogue: C/D layout col = lane&15, row = quad*4 + reg
    float* out = partial + (size_t)ks * BATCH * ODIM;
    #pragma unroll
    for (int mi = 0; mi < 4; ++mi)
        #pragma unroll
        for (int ni = 0; ni < 4; ++ni)
            #pragma unroll
            for (int r = 0; r < 4; ++r) {
                int rowg = wrow * 64 + mi * 16 + quad * 4 + r;
                int colg = nt * TN + wcol * 64 + ni * 16 + row;
                out[(size_t)rowg * ODIM + colg] = acc[mi][ni][r];
            }
}

// ---- kernel 3: sum KSPLIT partials + bias ----
__global__ void k_reduce_bias(const float* __restrict__ partial,
                              const float* __restrict__ bias,
                              float* __restrict__ out) {
    int t = blockIdx.x * 256 + threadIdx.x;
    const float4* b4 = (const float4*)bias;
    float4 c = b4[t & (ODIM / 4 - 1)];
    float4 r = {c.x, c.y, c.z, c.w};
    #pragma unroll
    for (int k = 0; k < KSPLIT; ++k) {
        const float4* p = (const float4*)(partial + (size_t)k * BATCH * ODIM);
        float4 a = p[t];
        r.x += a.x; r.y += a.y; r.z += a.z; r.w += a.w;
    }
    ((float4*)out)[t] = r;
}

extern "C" void kernel_launch(void* const* d_in, const int* in_sizes, int n_in,
                              void* d_out, int out_size, void* d_ws, size_t ws_size,
                              hipStream_t stream) {
    const float* x      = (const float*)d_in[0];
    const float* blocks = (const float*)d_in[1];
    const float* bias   = (const float*)d_in[2];
    const int*   parts  = (const int*)d_in[3];
    float* out = (float*)d_out;

    char* ws = (char*)d_ws;
    unsigned short* xb      = (unsigned short*)ws;                      // 4 MB
    unsigned short* btb     = (unsigned short*)(ws + (4u << 20));       // 8 MB
    int*            pTr     = (int*)(ws + (12u << 20));                 // 64 KB
    float*          partial = (float*)(ws + (13u << 20));               // 64 MB (8 x 8 MB)

    k_convert<<<NB + XCONV_BLKS + PT_BLKS, 256, 0, stream>>>(x, blocks, parts, xb, btb, pTr);
    k_mosaic_gemm<<<dim3(ODIM / TN, KSPLIT), 1024, 0, stream>>>(xb, btb, pTr, partial);
    k_reduce_bias<<<(BATCH * ODIM) / (256 * 4), 256, 0, stream>>>(partial, bias, out);
}

// Round 9
// 123.269 us; speedup vs baseline: 1.0180x; 1.0180x over previous
//
#include <hip/hip_runtime.h>
#include <stdint.h>

#define BATCH 256
#define IDIM  8192
#define ODIM  8192
#define MS    64
#define IC    128
#define OC    128
#define NB    1024

#define TM 128
#define TN 128
#define KSPLIT 4
#define NIB (IC / KSPLIT)      // 32 ib-iterations per workgroup

typedef __bf16 bf16x8 __attribute__((ext_vector_type(8)));
typedef float  floatx4 __attribute__((ext_vector_type(4)));

// s_waitcnt imm: vmcnt[3:0]|[15:14], expcnt/lgkmcnt = don't-care
#define WAITCNT_VM(n) ((((n) & 15) | (((n) >> 4) << 14)) | 0x70 | 0xF00)

__device__ __forceinline__ void async_load16(unsigned short* lds_p, const unsigned short* g_p) {
    __builtin_amdgcn_global_load_lds(
        (const __attribute__((address_space(1))) unsigned int*)g_p,
        (__attribute__((address_space(3))) unsigned int*)lds_p,
        16, 0, 0);
}

__device__ __forceinline__ unsigned short f32_to_bf16(float f) {
    unsigned int u = __float_as_uint(f);
    u += 0x7FFFu + ((u >> 16) & 1u);
    return (unsigned short)(u >> 16);
}

// ---- kernel 1: A -> MFMA-fragment order (R5-verified) | blocks -> [b][c][r] | parts -> pT ----
// A-frag: frag(g,ib,kk) at ushort offset ((g*128+ib)*2+kk)*512 + lane*8
//   lane L holds x[g*16 + (L&15)][ib*64 + kk*32 + (L>>4)*8 + j]
#define XCONV_BLKS 1024
#define PT_BLKS 64
__global__ void k_convert(const float* __restrict__ x, const float* __restrict__ blocks,
                          const int* __restrict__ parts,
                          unsigned short* __restrict__ xa, unsigned short* __restrict__ bt,
                          int* __restrict__ pT) {
    __shared__ float tile[MS][MS + 1];
    int b = blockIdx.x;
    if (b < NB) {
        const float4* src4 = (const float4*)(blocks + (size_t)b * MS * MS);
        unsigned short* dst = bt + (size_t)b * MS * MS;
        #pragma unroll
        for (int i = 0; i < 4; ++i) {
            int slot = i * 256 + threadIdx.x;
            int r = slot >> 4, c4 = (slot & 15) * 4;
            float4 v = src4[slot];
            tile[r][c4 + 0] = v.x; tile[r][c4 + 1] = v.y;
            tile[r][c4 + 2] = v.z; tile[r][c4 + 3] = v.w;
        }
        __syncthreads();
        #pragma unroll
        for (int i = 0; i < 2; ++i) {
            int slot = i * 256 + threadIdx.x;
            int c = slot >> 3, o = slot & 7;
            union { unsigned short s[8]; uint4 v; } u;
            #pragma unroll
            for (int j = 0; j < 8; ++j) u.s[j] = f32_to_bf16(tile[o * 8 + j][c]);
            *(uint4*)(dst + c * MS + o * 8) = u.v;        // bt[b][c][r]
        }
    } else if (b < NB + XCONV_BLKS) {
        int o = (b - NB) * 256 + threadIdx.x;             // 262144 fragment-slots
        int L = o & 63, kk = (o >> 6) & 1, ib = (o >> 7) & 127, g = o >> 14;
        int m  = g * 16 + (L & 15);
        int k0 = ib * 64 + kk * 32 + (L >> 4) * 8;
        const float* src = x + (size_t)m * IDIM + k0;
        float4 a = *(const float4*)src, c = *(const float4*)(src + 4);
        union { unsigned short s[8]; uint4 v; } u;
        u.s[0] = f32_to_bf16(a.x); u.s[1] = f32_to_bf16(a.y);
        u.s[2] = f32_to_bf16(a.z); u.s[3] = f32_to_bf16(a.w);
        u.s[4] = f32_to_bf16(c.x); u.s[5] = f32_to_bf16(c.y);
        u.s[6] = f32_to_bf16(c.z); u.s[7] = f32_to_bf16(c.w);
        *(uint4*)(xa + (size_t)o * 8) = u.v;
    } else {
        int t = (b - NB - XCONV_BLKS) * 256 + threadIdx.x;   // 16384
        int oc = t >> 7, ic = t & 127;
        pT[t] = parts[ic * OC + oc];                          // pT[ob][ib]
    }
}

// ---- kernel 2: GEMM 128x128. A: register-dbuf direct-from-L2. B: LDS-dbuf gather. ----
// LDS XOR swizzle on B (verified 0 conflicts).
__global__ __launch_bounds__(256, 2)
void k_mosaic_gemm(const unsigned short* __restrict__ xa,
                   const unsigned short* __restrict__ bt,
                   const int* __restrict__ pT,
                   float* __restrict__ partial) {
    __shared__ __align__(16) unsigned short b_lds[2][TN * MS];   // 2 x 16 KB (B only)

    const int tid  = threadIdx.x;
    const int lane = tid & 63;
    const int wave = tid >> 6;
    const int wrow = wave >> 1;      // 0..1 : 64-row band
    const int wcol = wave & 1;       // 0..1 : 64-col band
    const int nt = blockIdx.x;       // 0..63
    const int mt = blockIdx.y;       // 0..1
    const int ks = blockIdx.z;       // 0..3

    const int m0    = mt * TM;
    const int ob0   = nt * 2;
    const int ib0   = ks * NIB;
    const int gbase = mt * 8 + wrow * 4;   // A-frag group base (g = m/16)

    const int row  = lane & 15;
    const int quad = lane >> 4;

    // preload all 32 iterations' part indices into lane registers
    int pv0 = pT[ob0 * IC + ib0 + (lane & 31)];
    int pv1 = pT[(ob0 + 1) * IC + ib0 + (lane & 31)];

    // iteration-invariant B ds_read element offsets
    int b_off[2][4];
    #pragma unroll
    for (int kk = 0; kk < 2; ++kk) {
        int oct = kk * 4 + quad;
        #pragma unroll
        for (int ni = 0; ni < 4; ++ni) {
            int n = wcol * 64 + ni * 16 + row;
            b_off[kk][ni] = n * MS + ((oct ^ (n & 7)) << 3);
        }
    }

    floatx4 acc[4][4];
    #pragma unroll
    for (int mi = 0; mi < 4; ++mi)
        #pragma unroll
        for (int ni = 0; ni < 4; ++ni)
            acc[mi][ni] = (floatx4){0.f, 0.f, 0.f, 0.f};

    bf16x8 aA[4][2], aB[4][2];   // A-fragment ping-pong buffers

    // 4 global_load_lds per thread per B-stage — manual vmcnt counts rely on this
#define STAGE_B(buf, p0_, p1_) do {                                           \
    _Pragma("unroll")                                                         \
    for (int j = 0; j < 4; ++j) {                                             \
        int slot = j * 256 + tid;                                             \
        int n = slot >> 3;                                                    \
        int oct = (slot & 7) ^ (n & 7);                                       \
        int p = (j < 2) ? (p0_) : (p1_);                                      \
        async_load16(&b_lds[buf][slot * 8],                                   \
                     bt + (size_t)p * (MS * MS) + (n & 63) * MS + oct * 8);   \
    } } while (0)

    // 8 global_load_dwordx4 direct to regs (A is L2-resident, frag-ordered)
#define LOAD_A(dst, ib_) do {                                                 \
    _Pragma("unroll")                                                         \
    for (int mi = 0; mi < 4; ++mi)                                            \
    _Pragma("unroll")                                                         \
    for (int kk = 0; kk < 2; ++kk)                                            \
        dst[mi][kk] = *(const bf16x8*)(xa +                                   \
            (((size_t)(gbase + mi) * 128 + (ib_)) * 2 + kk) * 512 + lane * 8);\
    } while (0)

#define COMPUTE(buf, af) do {                                                 \
    _Pragma("unroll")                                                         \
    for (int kk = 0; kk < 2; ++kk) {                                          \
        bf16x8 bfr[4];                                                        \
        _Pragma("unroll")                                                     \
        for (int ni = 0; ni < 4; ++ni)                                        \
            bfr[ni] = *(const bf16x8*)&b_lds[buf][b_off[kk][ni]];             \
        _Pragma("unroll")                                                     \
        for (int mi = 0; mi < 4; ++mi)                                        \
            _Pragma("unroll")                                                 \
            for (int ni = 0; ni < 4; ++ni)                                    \
                acc[mi][ni] = __builtin_amdgcn_mfma_f32_16x16x32_bf16(        \
                    af[mi][kk], bfr[ni], acc[mi][ni], 0, 0, 0);               \
    } } while (0)

    // one pipelined iteration. NOTE: macro-local renamed `it` (R8 bug: `int i = (i_)`
    // with arg `i + 1` self-shadowed the initializer -> UB -> NaN).
#define ITER(i_, AC, AN) do {                                                 \
    int it = (i_);                                                            \
    if (it + 1 < NIB) {                                                       \
        int q0 = __shfl(pv0, it + 1), q1 = __shfl(pv1, it + 1);               \
        STAGE_B((it + 1) & 1, q0, q1);                                        \
        __builtin_amdgcn_sched_barrier(0);                                    \
        __builtin_amdgcn_s_waitcnt(WAITCNT_VM(4));                            \
    } else {                                                                  \
        __builtin_amdgcn_sched_barrier(0);                                    \
        __builtin_amdgcn_s_waitcnt(WAITCNT_VM(0));                            \
    }                                                                         \
    __builtin_amdgcn_s_barrier();                                             \
    if (it + 1 < NIB) LOAD_A(AN, ib0 + it + 1);                               \
    COMPUTE(it & 1, AC);                                                      \
    __builtin_amdgcn_s_barrier();                                             \
    } while (0)

    // prologue
    LOAD_A(aA, ib0);
    {
        int q0 = __shfl(pv0, 0), q1 = __shfl(pv1, 0);
        STAGE_B(0, q0, q1);
    }
    for (int i = 0; i < NIB; i += 2) {
        ITER(i,     aA, aB);
        ITER(i + 1, aB, aA);
    }

    // epilogue: C/D layout col = lane&15, row = quad*4 + reg
    float* out = partial + (size_t)ks * BATCH * ODIM;
    #pragma unroll
    for (int mi = 0; mi < 4; ++mi)
        #pragma unroll
        for (int ni = 0; ni < 4; ++ni)
            #pragma unroll
            for (int r = 0; r < 4; ++r) {
                int rowg = m0 + wrow * 64 + mi * 16 + quad * 4 + r;
                int colg = nt * TN + wcol * 64 + ni * 16 + row;
                out[(size_t)rowg * ODIM + colg] = acc[mi][ni][r];
            }
}

// ---- kernel 3: sum KSPLIT partials + bias ----
__global__ void k_reduce_bias(const float* __restrict__ partial,
                              const float* __restrict__ bias,
                              float* __restrict__ out) {
    int t = blockIdx.x * 256 + threadIdx.x;
    const float4* b4 = (const float4*)bias;
    float4 c = b4[t & (ODIM / 4 - 1)];
    float4 r = {c.x, c.y, c.z, c.w};
    #pragma unroll
    for (int k = 0; k < KSPLIT; ++k) {
        const float4* p = (const float4*)(partial + (size_t)k * BATCH * ODIM);
        float4 a = p[t];
        r.x += a.x; r.y += a.y; r.z += a.z; r.w += a.w;
    }
    ((float4*)out)[t] = r;
}

extern "C" void kernel_launch(void* const* d_in, const int* in_sizes, int n_in,
                              void* d_out, int out_size, void* d_ws, size_t ws_size,
                              hipStream_t stream) {
    const float* x      = (const float*)d_in[0];
    const float* blocks = (const float*)d_in[1];
    const float* bias   = (const float*)d_in[2];
    const int*   parts  = (const int*)d_in[3];
    float* out = (float*)d_out;

    char* ws = (char*)d_ws;
    unsigned short* xa      = (unsigned short*)ws;                      // 4 MB A-frags
    unsigned short* btb     = (unsigned short*)(ws + (4u << 20));       // 8 MB blocks_T
    int*            pTr     = (int*)(ws + (12u << 20));                 // 64 KB parts^T
    float*          partial = (float*)(ws + (13u << 20));               // 32 MB

    k_convert<<<NB + XCONV_BLKS + PT_BLKS, 256, 0, stream>>>(x, blocks, parts, xa, btb, pTr);
    k_mosaic_gemm<<<dim3(ODIM / TN, BATCH / TM, KSPLIT), 256, 0, stream>>>(xa, btb, pTr, partial);
    k_reduce_bias<<<(BATCH * ODIM) / (256 * 4), 256, 0, stream>>>(partial, bias, out);
}

// Round 10
// 118.919 us; speedup vs baseline: 1.0552x; 1.0366x over previous
//
#include <hip/hip_runtime.h>
#include <stdint.h>

#define BATCH 256
#define IDIM  8192
#define ODIM  8192
#define MS    64
#define IC    128
#define OC    128
#define NB    1024

#define TM 256
#define TN 128
#define KSPLIT 4
#define NIB (IC / KSPLIT)          // 32 ib-iterations per workgroup

#define STAGE_USH (48 * 1024 / 2)  // 24576 ushorts per ring stage (A 32KB + B 16KB)
#define B_OFF_USH (32 * 1024 / 2)  // B region starts at 16384 ushorts within a stage

typedef __bf16 bf16x8 __attribute__((ext_vector_type(8)));
typedef float  floatx4 __attribute__((ext_vector_type(4)));

// s_waitcnt imm: vmcnt[3:0]|[15:14], expcnt/lgkmcnt = don't-care
#define WAITCNT_VM(n) ((((n) & 15) | (((n) >> 4) << 14)) | 0x70 | 0xF00)

__device__ __forceinline__ void async_load16(unsigned short* lds_p, const unsigned short* g_p) {
    __builtin_amdgcn_global_load_lds(
        (const __attribute__((address_space(1))) unsigned int*)g_p,
        (__attribute__((address_space(3))) unsigned int*)lds_p,
        16, 0, 0);
}

__device__ __forceinline__ unsigned short f32_to_bf16(float f) {
    unsigned int u = __float_as_uint(f);
    u += 0x7FFFu + ((u >> 16) & 1u);
    return (unsigned short)(u >> 16);
}

// ---- kernel 1: blocks -> bf16 [b][c][r] | x -> bf16 row-major | parts -> pT[ob][ib] ----
#define XCONV_BLKS 1024
#define PT_BLKS 64
__global__ void k_convert(const float* __restrict__ x, const float* __restrict__ blocks,
                          const int* __restrict__ parts,
                          unsigned short* __restrict__ xb, unsigned short* __restrict__ bt,
                          int* __restrict__ pT) {
    __shared__ float tile[MS][MS + 1];
    int b = blockIdx.x;
    if (b < NB) {
        const float4* src4 = (const float4*)(blocks + (size_t)b * MS * MS);
        unsigned short* dst = bt + (size_t)b * MS * MS;
        #pragma unroll
        for (int i = 0; i < 4; ++i) {
            int slot = i * 256 + threadIdx.x;
            int r = slot >> 4, c4 = (slot & 15) * 4;
            float4 v = src4[slot];
            tile[r][c4 + 0] = v.x; tile[r][c4 + 1] = v.y;
            tile[r][c4 + 2] = v.z; tile[r][c4 + 3] = v.w;
        }
        __syncthreads();
        #pragma unroll
        for (int i = 0; i < 2; ++i) {
            int slot = i * 256 + threadIdx.x;
            int c = slot >> 3, o = slot & 7;
            union { unsigned short s[8]; uint4 v; } u;
            #pragma unroll
            for (int j = 0; j < 8; ++j) u.s[j] = f32_to_bf16(tile[o * 8 + j][c]);
            *(uint4*)(dst + c * MS + o * 8) = u.v;        // bt[b][c][r]
        }
    } else if (b < NB + XCONV_BLKS) {
        int t = (b - NB) * 256 + threadIdx.x;
        const float4* x4 = (const float4*)x;
        float4 a = x4[2 * t], bb = x4[2 * t + 1];
        union { unsigned short s[8]; uint4 v; } u;
        u.s[0] = f32_to_bf16(a.x);  u.s[1] = f32_to_bf16(a.y);
        u.s[2] = f32_to_bf16(a.z);  u.s[3] = f32_to_bf16(a.w);
        u.s[4] = f32_to_bf16(bb.x); u.s[5] = f32_to_bf16(bb.y);
        u.s[6] = f32_to_bf16(bb.z); u.s[7] = f32_to_bf16(bb.w);
        ((uint4*)xb)[t] = u.v;
    } else {
        int t = (b - NB - XCONV_BLKS) * 256 + threadIdx.x;   // 16384
        int oc = t >> 7, ic = t & 127;
        pT[t] = parts[ic * OC + oc];                          // pT[ob][ib]
    }
}

// ---- kernel 2: GEMM 256x128 tile, 8 waves of 64x64, RING-3 LDS pipeline ----
// Stage i+3 issued after compute(i): wait-for-stage-i covers ~2 full iterations
// of latency (>= HBM 900 cyc). vmcnt: steady 18 in flight, wait(12) retires stage i.
// LDS XOR swizzle (verified 0 conflicts): LDS[r][oct] = global[r][oct ^ (r&7)]
extern __shared__ unsigned short smem[];   // 3 x 48 KB = 144 KB dynamic

__global__ __launch_bounds__(512, 1)
void k_mosaic_gemm(const unsigned short* __restrict__ xb,
                   const unsigned short* __restrict__ bt,
                   const int* __restrict__ pT,
                   float* __restrict__ partial) {
    const int tid  = threadIdx.x;            // 0..511
    const int lane = tid & 63;
    const int wave = tid >> 6;               // 0..7
    const int wrow = wave >> 1;              // 0..3 : 64-row band of 256
    const int wcol = wave & 1;               // 0..1 : 64-col band of 128
    const int nt = blockIdx.x;               // 0..63
    const int ks = blockIdx.y;               // 0..3

    const int ob0 = nt * 2;
    const int ib0 = ks * NIB;

    const int row  = lane & 15;
    const int quad = lane >> 4;

    // preload all 32 iterations' part indices into lane registers
    int pv0 = pT[ob0 * IC + ib0 + (lane & 31)];
    int pv1 = pT[(ob0 + 1) * IC + ib0 + (lane & 31)];

    // iteration-invariant ds_read element offsets (relative to stage base)
    int a_off[2][4], b_off[2][4];
    #pragma unroll
    for (int kk = 0; kk < 2; ++kk) {
        int oct = kk * 4 + quad;
        #pragma unroll
        for (int mi = 0; mi < 4; ++mi) {
            int r = wrow * 64 + mi * 16 + row;
            a_off[kk][mi] = r * MS + ((oct ^ (r & 7)) << 3);
        }
        #pragma unroll
        for (int ni = 0; ni < 4; ++ni) {
            int n = wcol * 64 + ni * 16 + row;
            b_off[kk][ni] = B_OFF_USH + n * MS + ((oct ^ (n & 7)) << 3);
        }
    }

    floatx4 acc[4][4];
    #pragma unroll
    for (int mi = 0; mi < 4; ++mi)
        #pragma unroll
        for (int ni = 0; ni < 4; ++ni)
            acc[mi][ni] = (floatx4){0.f, 0.f, 0.f, 0.f};

    // 6 global_load_lds per thread per stage (4 A + 2 B) — vmcnt counts rely on this
#define STAGE(base, ib_, p0_, p1_) do {                                       \
    _Pragma("unroll")                                                         \
    for (int j = 0; j < 4; ++j) {                                             \
        int slot = j * 512 + tid;              /* 2048: 256 rows x 8 octets */ \
        int m = slot >> 3;                                                    \
        int oct = (slot & 7) ^ (m & 7);                                       \
        async_load16(smem + (base) + slot * 8,                                \
                     xb + (size_t)m * IDIM + (ib_) * MS + oct * 8);           \
    }                                                                         \
    _Pragma("unroll")                                                         \
    for (int j = 0; j < 2; ++j) {                                             \
        int slot = j * 512 + tid;              /* 1024: 128 rows x 8 octets */ \
        int n = slot >> 3;                                                    \
        int oct = (slot & 7) ^ (n & 7);                                       \
        int p = (j == 0) ? (p0_) : (p1_);                                     \
        async_load16(smem + (base) + B_OFF_USH + slot * 8,                    \
                     bt + (size_t)p * (MS * MS) + (n & 63) * MS + oct * 8);   \
    } } while (0)

#define COMPUTE(base) do {                                                    \
    _Pragma("unroll")                                                         \
    for (int kk = 0; kk < 2; ++kk) {                                          \
        bf16x8 af[4], bfr[4];                                                 \
        _Pragma("unroll")                                                     \
        for (int mi = 0; mi < 4; ++mi)                                        \
            af[mi] = *(const bf16x8*)(smem + (base) + a_off[kk][mi]);         \
        _Pragma("unroll")                                                     \
        for (int ni = 0; ni < 4; ++ni)                                        \
            bfr[ni] = *(const bf16x8*)(smem + (base) + b_off[kk][ni]);        \
        _Pragma("unroll")                                                     \
        for (int mi = 0; mi < 4; ++mi)                                        \
            _Pragma("unroll")                                                 \
            for (int ni = 0; ni < 4; ++ni)                                    \
                acc[mi][ni] = __builtin_amdgcn_mfma_f32_16x16x32_bf16(        \
                    af[mi], bfr[ni], acc[mi][ni], 0, 0, 0);                   \
    } } while (0)

    // prologue: stage iters 0,1,2 into ring slots 0,1,2  (18 ops in flight)
    {
        int q0 = __shfl(pv0, 0), q1 = __shfl(pv1, 0);
        STAGE(0, ib0 + 0, q0, q1);
        q0 = __shfl(pv0, 1); q1 = __shfl(pv1, 1);
        STAGE(STAGE_USH, ib0 + 1, q0, q1);
        q0 = __shfl(pv0, 2); q1 = __shfl(pv1, 2);
        STAGE(2 * STAGE_USH, ib0 + 2, q0, q1);
    }

    int base = 0;
    for (int i = 0; i < NIB - 3; ++i) {
        __builtin_amdgcn_sched_barrier(0);
        __builtin_amdgcn_s_waitcnt(WAITCNT_VM(12));   // retire stage i; i+1,i+2 stay in flight
        __builtin_amdgcn_s_barrier();
        COMPUTE(base);
        __builtin_amdgcn_s_barrier();                  // all waves done with ring slot
        int q0 = __shfl(pv0, i + 3), q1 = __shfl(pv1, i + 3);
        STAGE(base, ib0 + i + 3, q0, q1);              // reuse slot for iter i+3
        base = (base == 2 * STAGE_USH) ? 0 : base + STAGE_USH;
    }
    // peeled tail: i = NIB-3 (18 in flight), NIB-2 (12), NIB-1 (6)
    __builtin_amdgcn_sched_barrier(0);
    __builtin_amdgcn_s_waitcnt(WAITCNT_VM(12));
    __builtin_amdgcn_s_barrier();
    COMPUTE(base);
    __builtin_amdgcn_s_barrier();
    base = (base == 2 * STAGE_USH) ? 0 : base + STAGE_USH;

    __builtin_amdgcn_sched_barrier(0);
    __builtin_amdgcn_s_waitcnt(WAITCNT_VM(6));
    __builtin_amdgcn_s_barrier();
    COMPUTE(base);
    __builtin_amdgcn_s_barrier();
    base = (base == 2 * STAGE_USH) ? 0 : base + STAGE_USH;

    __builtin_amdgcn_sched_barrier(0);
    __builtin_amdgcn_s_waitcnt(WAITCNT_VM(0));
    __builtin_amdgcn_s_barrier();
    COMPUTE(base);

    // epilogue: C/D layout col = lane&15, row = quad*4 + reg
    float* out = partial + (size_t)ks * BATCH * ODIM;
    #pragma unroll
    for (int mi = 0; mi < 4; ++mi)
        #pragma unroll
        for (int ni = 0; ni < 4; ++ni)
            #pragma unroll
            for (int r = 0; r < 4; ++r) {
                int rowg = wrow * 64 + mi * 16 + quad * 4 + r;
                int colg = nt * TN + wcol * 64 + ni * 16 + row;
                out[(size_t)rowg * ODIM + colg] = acc[mi][ni][r];
            }
}

// ---- kernel 3: sum KSPLIT partials + bias ----
__global__ void k_reduce_bias(const float* __restrict__ partial,
                              const float* __restrict__ bias,
                              float* __restrict__ out) {
    int t = blockIdx.x * 256 + threadIdx.x;
    const float4* b4 = (const float4*)bias;
    float4 c = b4[t & (ODIM / 4 - 1)];
    float4 r = {c.x, c.y, c.z, c.w};
    #pragma unroll
    for (int k = 0; k < KSPLIT; ++k) {
        const float4* p = (const float4*)(partial + (size_t)k * BATCH * ODIM);
        float4 a = p[t];
        r.x += a.x; r.y += a.y; r.z += a.z; r.w += a.w;
    }
    ((float4*)out)[t] = r;
}

extern "C" void kernel_launch(void* const* d_in, const int* in_sizes, int n_in,
                              void* d_out, int out_size, void* d_ws, size_t ws_size,
                              hipStream_t stream) {
    const float* x      = (const float*)d_in[0];
    const float* blocks = (const float*)d_in[1];
    const float* bias   = (const float*)d_in[2];
    const int*   parts  = (const int*)d_in[3];
    float* out = (float*)d_out;

    char* ws = (char*)d_ws;
    unsigned short* xb      = (unsigned short*)ws;                      // 4 MB
    unsigned short* btb     = (unsigned short*)(ws + (4u << 20));       // 8 MB
    int*            pTr     = (int*)(ws + (12u << 20));                 // 64 KB
    float*          partial = (float*)(ws + (13u << 20));               // 32 MB

    // allow 144 KB dynamic LDS (idempotent; host-side, graph-capture safe)
    static bool attr_set = false;
    if (!attr_set) {
        hipFuncSetAttribute((const void*)k_mosaic_gemm,
                            hipFuncAttributeMaxDynamicSharedMemorySize, 3 * 48 * 1024);
        attr_set = true;
    }

    k_convert<<<NB + XCONV_BLKS + PT_BLKS, 256, 0, stream>>>(x, blocks, parts, xb, btb, pTr);
    k_mosaic_gemm<<<dim3(ODIM / TN, KSPLIT), 512, 3 * 48 * 1024, stream>>>(xb, btb, pTr, partial);
    k_reduce_bias<<<(BATCH * ODIM) / (256 * 4), 256, 0, stream>>>(partial, bias, out);
}

// Round 12
// 118.802 us; speedup vs baseline: 1.0563x; 1.0010x over previous
//
#include <hip/hip_runtime.h>
#include <stdint.h>

#define BATCH 256
#define IDIM  8192
#define ODIM  8192
#define MS    64
#define IC    128
#define OC    128
#define NB    1024

#define TM 128
#define TN 128
#define KSPLIT 4
#define NIB (IC / KSPLIT)          // 32 rounds per workgroup

// dynamic LDS layout (ushort offsets): A dbuf 2 x 8192, B ring-3 3 x 8192 = 80 KB
#define A_BASE(s) ((s) * 8192)
#define B_BASE(s) (16384 + (s) * 8192)

typedef __bf16 bf16x8 __attribute__((ext_vector_type(8)));
typedef float  floatx4 __attribute__((ext_vector_type(4)));

// s_waitcnt imm: vmcnt[3:0]|[15:14], expcnt/lgkmcnt = don't-care
#define WAITCNT_VM(n) ((((n) & 15) | (((n) >> 4) << 14)) | 0x70 | 0xF00)

__device__ __forceinline__ void async_load16(unsigned short* lds_p, const unsigned short* g_p) {
    __builtin_amdgcn_global_load_lds(
        (const __attribute__((address_space(1))) unsigned int*)g_p,
        (__attribute__((address_space(3))) unsigned int*)lds_p,
        16, 0, 0);
}

__device__ __forceinline__ unsigned short f32_to_bf16(float f) {
    unsigned int u = __float_as_uint(f);
    u += 0x7FFFu + ((u >> 16) & 1u);
    return (unsigned short)(u >> 16);
}

// ---- kernel 1: blocks -> bf16 [b][c][r] | x -> bf16 row-major | parts -> pT[ob][ib] ----
#define XCONV_BLKS 1024
#define PT_BLKS 64
__global__ void k_convert(const float* __restrict__ x, const float* __restrict__ blocks,
                          const int* __restrict__ parts,
                          unsigned short* __restrict__ xb, unsigned short* __restrict__ bt,
                          int* __restrict__ pT) {
    __shared__ float tile[MS][MS + 1];
    int b = blockIdx.x;
    if (b < NB) {
        const float4* src4 = (const float4*)(blocks + (size_t)b * MS * MS);
        unsigned short* dst = bt + (size_t)b * MS * MS;
        #pragma unroll
        for (int i = 0; i < 4; ++i) {
            int slot = i * 256 + threadIdx.x;
            int r = slot >> 4, c4 = (slot & 15) * 4;
            float4 v = src4[slot];
            tile[r][c4 + 0] = v.x; tile[r][c4 + 1] = v.y;
            tile[r][c4 + 2] = v.z; tile[r][c4 + 3] = v.w;
        }
        __syncthreads();
        #pragma unroll
        for (int i = 0; i < 2; ++i) {
            int slot = i * 256 + threadIdx.x;
            int c = slot >> 3, o = slot & 7;
            union { unsigned short s[8]; uint4 v; } u;
            #pragma unroll
            for (int j = 0; j < 8; ++j) u.s[j] = f32_to_bf16(tile[o * 8 + j][c]);
            *(uint4*)(dst + c * MS + o * 8) = u.v;        // bt[b][c][r]
        }
    } else if (b < NB + XCONV_BLKS) {
        int t = (b - NB) * 256 + threadIdx.x;
        const float4* x4 = (const float4*)x;
        float4 a = x4[2 * t], bb = x4[2 * t + 1];
        union { unsigned short s[8]; uint4 v; } u;
        u.s[0] = f32_to_bf16(a.x);  u.s[1] = f32_to_bf16(a.y);
        u.s[2] = f32_to_bf16(a.z);  u.s[3] = f32_to_bf16(a.w);
        u.s[4] = f32_to_bf16(bb.x); u.s[5] = f32_to_bf16(bb.y);
        u.s[6] = f32_to_bf16(bb.z); u.s[7] = f32_to_bf16(bb.w);
        ((uint4*)xb)[t] = u.v;
    } else {
        int t = (b - NB - XCONV_BLKS) * 256 + threadIdx.x;   // 16384
        int oc = t >> 7, ic = t & 127;
        pT[t] = parts[ic * OC + oc];                          // pT[ob][ib]
    }
}

// ---- kernel 2: GEMM 128x128. A dbuf(depth-1) + B ring-3(depth-2), 2 wg/CU,
//      compile-time slots (6-round unroll), sched_barrier-pinned region order. ----
// Round i: stage A_{i+1}->slot (i+1)&1, B_{i+2}->slot (i+2)%3; wait vmcnt(12)
// retires exactly A_i,B_i; compute A slot i&1, B slot i%3.
// LDS XOR swizzle (verified 0 conflicts): LDS[r][oct] = global[r][oct ^ (r&7)]
extern __shared__ unsigned short smem[];   // 80 KB dynamic

__global__ __launch_bounds__(256, 2)
void k_mosaic_gemm(const unsigned short* __restrict__ xb,
                   const unsigned short* __restrict__ bt,
                   const int* __restrict__ pT,
                   float* __restrict__ partial) {
    const int tid  = threadIdx.x;
    const int lane = tid & 63;
    const int wave = tid >> 6;
    const int wrow = wave >> 1;      // 0..1 : 64-row band
    const int wcol = wave & 1;       // 0..1 : 64-col band
    const int nt = blockIdx.x;       // 0..63
    const int mt = blockIdx.y;       // 0..1
    const int ks = blockIdx.z;       // 0..3

    const int m0  = mt * TM;
    const int ob0 = nt * 2;
    const int ib0 = ks * NIB;

    const int row  = lane & 15;
    const int quad = lane >> 4;

    // preload all 32 rounds' part indices into lane registers
    int pv0 = pT[ob0 * IC + ib0 + (lane & 31)];
    int pv1 = pT[(ob0 + 1) * IC + ib0 + (lane & 31)];

    // iteration-invariant ds_read element offsets (relative to stage base)
    int a_off[2][4], b_off[2][4];
    #pragma unroll
    for (int kk = 0; kk < 2; ++kk) {
        int oct = kk * 4 + quad;
        #pragma unroll
        for (int mi = 0; mi < 4; ++mi) {
            int r = wrow * 64 + mi * 16 + row;
            a_off[kk][mi] = r * MS + ((oct ^ (r & 7)) << 3);
        }
        #pragma unroll
        for (int ni = 0; ni < 4; ++ni) {
            int n = wcol * 64 + ni * 16 + row;
            b_off[kk][ni] = n * MS + ((oct ^ (n & 7)) << 3);
        }
    }

    floatx4 acc[4][4];
    #pragma unroll
    for (int mi = 0; mi < 4; ++mi)
        #pragma unroll
        for (int ni = 0; ni < 4; ++ni)
            acc[mi][ni] = (floatx4){0.f, 0.f, 0.f, 0.f};

    // 4 global_load_lds per thread per A-stage / per B-stage — vmcnt math relies on this
#define STAGE_A(abase, ibx) do {                                              \
    _Pragma("unroll")                                                         \
    for (int j = 0; j < 4; ++j) {                                             \
        int slot = j * 256 + tid;              /* 1024: 128 rows x 8 octets */ \
        int m = slot >> 3;                                                    \
        int oct = (slot & 7) ^ (m & 7);                                       \
        async_load16(smem + (abase) + slot * 8,                               \
                     xb + (size_t)(m0 + m) * IDIM + (ibx) * MS + oct * 8);    \
    } } while (0)

#define STAGE_B(bbase, pa, pb) do {                                           \
    _Pragma("unroll")                                                         \
    for (int j = 0; j < 4; ++j) {                                             \
        int slot = j * 256 + tid;              /* 1024: 128 rows x 8 octets */ \
        int n = slot >> 3;                                                    \
        int oct = (slot & 7) ^ (n & 7);                                       \
        int p = (j < 2) ? (pa) : (pb);                                        \
        async_load16(smem + (bbase) + slot * 8,                               \
                     bt + (size_t)p * (MS * MS) + (n & 63) * MS + oct * 8);   \
    } } while (0)

#define COMPUTE(abase, bbase) do {                                            \
    _Pragma("unroll")                                                         \
    for (int kk = 0; kk < 2; ++kk) {                                          \
        bf16x8 af[4], bfr[4];                                                 \
        _Pragma("unroll")                                                     \
        for (int mi = 0; mi < 4; ++mi)                                        \
            af[mi] = *(const bf16x8*)(smem + (abase) + a_off[kk][mi]);        \
        _Pragma("unroll")                                                     \
        for (int ni = 0; ni < 4; ++ni)                                        \
            bfr[ni] = *(const bf16x8*)(smem + (bbase) + b_off[kk][ni]);       \
        _Pragma("unroll")                                                     \
        for (int mi = 0; mi < 4; ++mi)                                        \
            _Pragma("unroll")                                                 \
            for (int ni = 0; ni < 4; ++ni)                                    \
                acc[mi][ni] = __builtin_amdgcn_mfma_f32_16x16x32_bf16(        \
                    af[mi], bfr[ni], acc[mi][ni], 0, 0, 0);                   \
    } } while (0)

    // one fully-pinned round; slot args are LITERAL constants at every call site
#define ROUND(idx, acS, bcS, asS, bsS) do {                                   \
    STAGE_A(A_BASE(asS), ib0 + (idx) + 1);                                    \
    { int q0 = __shfl(pv0, (idx) + 2), q1 = __shfl(pv1, (idx) + 2);           \
      STAGE_B(B_BASE(bsS), q0, q1); }                                         \
    __builtin_amdgcn_sched_barrier(0);                                        \
    __builtin_amdgcn_s_waitcnt(WAITCNT_VM(12));                               \
    __builtin_amdgcn_s_barrier();                                             \
    __builtin_amdgcn_sched_barrier(0);                                        \
    COMPUTE(A_BASE(acS), B_BASE(bcS));                                        \
    __builtin_amdgcn_sched_barrier(0);                                        \
    __builtin_amdgcn_s_barrier();                                             \
    __builtin_amdgcn_sched_barrier(0);                                        \
    } while (0)

    // prologue: queue = [A0, B0, B1]  (12 ops in flight)
    STAGE_A(A_BASE(0), ib0 + 0);
    { int q0 = __shfl(pv0, 0), q1 = __shfl(pv1, 0); STAGE_B(B_BASE(0), q0, q1); }
    { int q0 = __shfl(pv0, 1), q1 = __shfl(pv1, 1); STAGE_B(B_BASE(1), q0, q1); }

    // steady rounds 0..29: 5 x 6-round unroll; (i6 even, i6 % 3 == 0) keeps slot
    // patterns exact: compute A slot r&1 / B slot r%3, stage A (r+1)&1 / B (r+2)%3
    for (int i6 = 0; i6 < 30; i6 += 6) {
        ROUND(i6 + 0, 0, 0, 1, 2);
        ROUND(i6 + 1, 1, 1, 0, 0);
        ROUND(i6 + 2, 0, 2, 1, 1);
        ROUND(i6 + 3, 1, 0, 0, 2);
        ROUND(i6 + 4, 0, 1, 1, 0);
        ROUND(i6 + 5, 1, 2, 0, 1);
    }
    // round 30: stage A31 -> slot 1; retire B30,A30 (8 younger: B31,A31); compute A@0,B@0
    STAGE_A(A_BASE(1), ib0 + NIB - 1);
    __builtin_amdgcn_sched_barrier(0);
    __builtin_amdgcn_s_waitcnt(WAITCNT_VM(8));
    __builtin_amdgcn_s_barrier();
    __builtin_amdgcn_sched_barrier(0);
    COMPUTE(A_BASE(0), B_BASE(0));
    __builtin_amdgcn_sched_barrier(0);
    __builtin_amdgcn_s_barrier();
    __builtin_amdgcn_sched_barrier(0);
    // round 31: retire everything; compute A@1,B@1
    __builtin_amdgcn_s_waitcnt(WAITCNT_VM(0));
    __builtin_amdgcn_s_barrier();
    __builtin_amdgcn_sched_barrier(0);
    COMPUTE(A_BASE(1), B_BASE(1));

    // epilogue: C/D layout col = lane&15, row = quad*4 + reg
    float* out = partial + (size_t)ks * BATCH * ODIM;
    #pragma unroll
    for (int mi = 0; mi < 4; ++mi)
        #pragma unroll
        for (int ni = 0; ni < 4; ++ni)
            #pragma unroll
            for (int r = 0; r < 4; ++r) {
                int rowg = m0 + wrow * 64 + mi * 16 + quad * 4 + r;
                int colg = nt * TN + wcol * 64 + ni * 16 + row;
                out[(size_t)rowg * ODIM + colg] = acc[mi][ni][r];
            }
}

// ---- kernel 3: sum KSPLIT partials + bias ----
__global__ void k_reduce_bias(const float* __restrict__ partial,
                              const float* __restrict__ bias,
                              float* __restrict__ out) {
    int t = blockIdx.x * 256 + threadIdx.x;
    const float4* b4 = (const float4*)bias;
    float4 c = b4[t & (ODIM / 4 - 1)];
    float4 r = {c.x, c.y, c.z, c.w};
    #pragma unroll
    for (int k = 0; k < KSPLIT; ++k) {
        const float4* p = (const float4*)(partial + (size_t)k * BATCH * ODIM);
        float4 a = p[t];
        r.x += a.x; r.y += a.y; r.z += a.z; r.w += a.w;
    }
    ((float4*)out)[t] = r;
}

extern "C" void kernel_launch(void* const* d_in, const int* in_sizes, int n_in,
                              void* d_out, int out_size, void* d_ws, size_t ws_size,
                              hipStream_t stream) {
    const float* x      = (const float*)d_in[0];
    const float* blocks = (const float*)d_in[1];
    const float* bias   = (const float*)d_in[2];
    const int*   parts  = (const int*)d_in[3];
    float* out = (float*)d_out;

    char* ws = (char*)d_ws;
    unsigned short* xb      = (unsigned short*)ws;                      // 4 MB
    unsigned short* btb     = (unsigned short*)(ws + (4u << 20));       // 8 MB
    int*            pTr     = (int*)(ws + (12u << 20));                 // 64 KB
    float*          partial = (float*)(ws + (13u << 20));               // 32 MB

    // allow 80 KB dynamic LDS (idempotent; host-side, graph-capture safe)
    static bool attr_set = false;
    if (!attr_set) {
        hipFuncSetAttribute((const void*)k_mosaic_gemm,
                            hipFuncAttributeMaxDynamicSharedMemorySize, 80 * 1024);
        attr_set = true;
    }

    k_convert<<<NB + XCONV_BLKS + PT_BLKS, 256, 0, stream>>>(x, blocks, parts, xb, btb, pTr);
    k_mosaic_gemm<<<dim3(ODIM / TN, BATCH / TM, KSPLIT), 256, 80 * 1024, stream>>>(xb, btb, pTr, partial);
    k_reduce_bias<<<(BATCH * ODIM) / (256 * 4), 256, 0, stream>>>(partial, bias, out);
}